// Round 4
// baseline (216.418 us; speedup 1.0000x reference)
//
#include <hip/hip_runtime.h>
#include <math.h>

#define D 768
#define NE 8
#define NTOK 6192      // 32*129 + 16*129
#define MEN_TOK0 4128  // 32*129
#define NCBLK 25       // ceil(6192/256)

typedef __attribute__((ext_vector_type(8))) short short8;   // 8 x bf16
typedef __attribute__((ext_vector_type(4))) short short4b;  // 4 x bf16
typedef __attribute__((ext_vector_type(4))) float floatx4;  // MFMA C/D

__device__ __forceinline__ short f2bf(float f) {
  union { float f; unsigned u; } x; x.f = f;
  unsigned r = x.u + 0x7fffu + ((x.u >> 16) & 1u);
  return (short)(r >> 16);
}
__device__ __forceinline__ float bf2f(short s) {
  union { unsigned u; float f; } x; x.u = ((unsigned)(unsigned short)s) << 16;
  return x.f;
}

// Map concatenated token index -> source row pointer (virtual concat, no copy).
__device__ __forceinline__ const float* token_row(int t,
    const float* __restrict__ ecls, const float* __restrict__ etok,
    const float* __restrict__ mcls, const float* __restrict__ mtok) {
  if (t < MEN_TOK0) {
    int n = t / 129, s = t - n * 129;
    return (s == 0) ? (ecls + n * D) : (etok + (size_t)(n * 128 + s - 1) * D);
  } else {
    int tm = t - MEN_TOK0;
    int b = tm / 129, s = tm - b * 129;
    return (s == 0) ? (mcls + b * D) : (mtok + (size_t)(b * 128 + s - 1) * D);
  }
}

// ---------------- gate logits + top-2 + token bf16 materialization (Xb)
__global__ __launch_bounds__(256) void gate_kernel(
    const float* __restrict__ ecls, const float* __restrict__ etok,
    const float* __restrict__ mcls, const float* __restrict__ mtok,
    const float* __restrict__ gate_w, const float* __restrict__ gate_b,
    int* __restrict__ te1, int* __restrict__ te2,
    float* __restrict__ tw1, float* __restrict__ tw2,
    short* __restrict__ Xb) {
  int t = blockIdx.x * 4 + (threadIdx.x >> 6);
  int lane = threadIdx.x & 63;
  const float* xr = token_row(t, ecls, etok, mcls, mtok);
  float acc[NE];
#pragma unroll
  for (int e = 0; e < NE; ++e) acc[e] = 0.f;
#pragma unroll
  for (int it = 0; it < 3; ++it) {
    int d0 = lane * 4 + it * 256;
    floatx4 x = *(const floatx4*)(xr + d0);
    short4b xb;
#pragma unroll
    for (int q = 0; q < 4; ++q) {
      xb[q] = f2bf(x[q]);
      float xv = x[q];
#pragma unroll
      for (int e = 0; e < NE; ++e) acc[e] += xv * gate_w[(d0 + q) * NE + e];
    }
    *(short4b*)(Xb + (size_t)t * D + d0) = xb;
  }
#pragma unroll
  for (int e = 0; e < NE; ++e) {
#pragma unroll
    for (int off = 32; off > 0; off >>= 1) acc[e] += __shfl_down(acc[e], off);
  }
  if (lane == 0) {
    float lg[NE];
#pragma unroll
    for (int e = 0; e < NE; ++e) lg[e] = acc[e] + gate_b[e];
    int e1 = 0;
#pragma unroll
    for (int e = 1; e < NE; ++e) if (lg[e] > lg[e1]) e1 = e;
    int e2 = (e1 == 0) ? 1 : 0;
#pragma unroll
    for (int e = 0; e < NE; ++e) {
      if (e != e1 && lg[e] > lg[e2]) e2 = e;
    }
    float w1 = 1.f / (1.f + __expf(lg[e2] - lg[e1]));
    te1[t] = e1; te2[t] = e2;
    tw1[t] = w1; tw2[t] = 1.f - w1;
  }
}

// ---------------- per-block expert histograms (LDS atomics only)
__global__ __launch_bounds__(256) void count_kernel(
    const int* __restrict__ te1, const int* __restrict__ te2,
    int* __restrict__ localcnt) {
  __shared__ int h[NE];
  int tid = threadIdx.x;
  if (tid < NE) h[tid] = 0;
  __syncthreads();
  int t = blockIdx.x * 256 + tid;
  if (t < NTOK) {
    atomicAdd(&h[te1[t]], 1);
    atomicAdd(&h[te2[t]], 1);
  }
  __syncthreads();
  if (tid < NE) localcnt[blockIdx.x * NE + tid] = h[tid];
}

// ---------------- compact: global per-expert-contiguous slot assignment
__global__ __launch_bounds__(256) void compact_kernel(
    const int* __restrict__ te1, const int* __restrict__ te2,
    const int* __restrict__ localcnt,
    int* __restrict__ lst_tok, int* __restrict__ slot1, int* __restrict__ slot2,
    int* __restrict__ cnt, int* __restrict__ basee) {
  __shared__ int lc[NCBLK * NE];
  __shared__ int gbase[NE];
  __shared__ int ctr[NE];
  int tid = threadIdx.x;
  for (int i = tid; i < NCBLK * NE; i += 256) lc[i] = localcnt[i];
  if (tid < NE) ctr[tid] = 0;
  __syncthreads();
  if (tid < NE) {
    int e = tid;
    int mytotal = 0, myblockpre = 0;
    for (int j = 0; j < NCBLK; ++j) {
      int v = lc[j * NE + e];
      mytotal += v;
      if (j < (int)blockIdx.x) myblockpre += v;
    }
    int eb = 0;
    for (int ep = 0; ep < e; ++ep) {
      int tt = 0;
      for (int j = 0; j < NCBLK; ++j) tt += lc[j * NE + ep];
      eb += tt;
    }
    gbase[e] = eb + myblockpre;
    if (blockIdx.x == 0) { cnt[e] = mytotal; basee[e] = eb; }
  }
  __syncthreads();
  int t = blockIdx.x * 256 + tid;
  if (t < NTOK) {
    int e1 = te1[t], e2 = te2[t];
    int r1 = atomicAdd(&ctr[e1], 1);
    int r2 = atomicAdd(&ctr[e2], 1);
    int s1 = gbase[e1] + r1;
    int s2 = gbase[e2] + r2;
    slot1[t] = s1; slot2[t] = s2;
    lst_tok[s1] = t; lst_tok[s2] = t;
  }
}

// ---------------- transpose + fp32->bf16 convert of weight matrices
__global__ __launch_bounds__(256) void tcvt_kernel(
    const float* __restrict__ exp_w, const float* __restrict__ wq,
    const float* __restrict__ wk, const float* __restrict__ wv,
    short* __restrict__ expwT, short* __restrict__ wT) {
  int z = blockIdx.z;
  const float* src; short* dst;
  if (z < 8) { src = exp_w + (size_t)z * D * D; dst = expwT + (size_t)z * D * D; }
  else { src = (z == 8) ? wq : (z == 9) ? wk : wv; dst = wT + (size_t)(z - 8) * D * D; }
  int k0 = blockIdx.x * 64, o0 = blockIdx.y * 64;
  __shared__ float t[64][65];
  int tid = threadIdx.x;
  int tx = tid & 63, ty = tid >> 6;
#pragma unroll
  for (int i = 0; i < 16; ++i) {
    int k = i * 4 + ty;
    t[k][tx] = src[(size_t)(k0 + k) * D + o0 + tx];
  }
  __syncthreads();
#pragma unroll
  for (int i = 0; i < 16; ++i) {
    int o = i * 4 + ty;
    dst[(size_t)(o0 + o) * D + k0 + tx] = f2bf(t[tx][o]);
  }
}

// ---------------- grouped expert GEMM (MFMA bf16), 128x256 tile
// flattened grid: e = id&7 (XCD pinning), then ob (3), tb (49)
__global__ __launch_bounds__(256) void moe_kernel(
    const short* __restrict__ Xb, const short* __restrict__ expwT,
    const int* __restrict__ cnt, const int* __restrict__ basee,
    const int* __restrict__ lst_tok, short* __restrict__ EO) {
  int id = blockIdx.x;
  int e = id & 7;
  int r = id >> 3;          // 0..146
  int ob = r % 3;
  int tb = r / 3;           // 0..48
  int count = cnt[e];
  int t0 = tb * 128;
  if (t0 >= count) return;
  int o0 = ob * 256;
  int gb = basee[e];

  __shared__ short8 As[1024];   // 128 rows x 8 chunks, XOR-swizzled
  __shared__ short8 Bs[2048];   // 256 rows x 8 chunks
  __shared__ int stok[128];

  int tid = threadIdx.x;
  int l = tid & 63, w = tid >> 6;
  int wr = w >> 1, wc = w & 1;

  if (tid < 128) {
    int p = t0 + tid;
    stok[tid] = lst_tok[gb + (p < count ? p : 0)];
  }

  floatx4 acc[4][8];
#pragma unroll
  for (int ai = 0; ai < 4; ++ai)
#pragma unroll
    for (int bj = 0; bj < 8; ++bj) acc[ai][bj] = (floatx4){0.f, 0.f, 0.f, 0.f};

  const short* Bg = expwT + (size_t)e * D * D;

  for (int k0 = 0; k0 < D; k0 += 64) {
    __syncthreads();
#pragma unroll
    for (int q = 0; q < 4; ++q) {
      int p = q * 256 + tid;
      int row = p >> 3, c = p & 7;
      As[(row << 3) + (c ^ (row & 7))] =
          *(const short8*)(Xb + (size_t)stok[row] * D + k0 + c * 8);
    }
#pragma unroll
    for (int q = 0; q < 8; ++q) {
      int p = q * 256 + tid;
      int row = p >> 3, c = p & 7;
      Bs[(row << 3) + (c ^ (row & 7))] =
          *(const short8*)(Bg + (size_t)(o0 + row) * D + k0 + c * 8);
    }
    __syncthreads();
#pragma unroll
    for (int kk = 0; kk < 2; ++kk) {
      int kc = kk * 4 + (l >> 4);
      short8 a[4], bb[8];
#pragma unroll
      for (int ai = 0; ai < 4; ++ai) {
        int ar = wr * 64 + ai * 16 + (l & 15);
        a[ai] = As[(ar << 3) + (kc ^ (ar & 7))];
      }
#pragma unroll
      for (int bj = 0; bj < 8; ++bj) {
        int br = wc * 128 + bj * 16 + (l & 15);
        bb[bj] = Bs[(br << 3) + (kc ^ (br & 7))];
      }
#pragma unroll
      for (int ai = 0; ai < 4; ++ai)
#pragma unroll
        for (int bj = 0; bj < 8; ++bj)
          acc[ai][bj] = __builtin_amdgcn_mfma_f32_16x16x32_bf16(a[ai], bb[bj], acc[ai][bj], 0, 0, 0);
    }
  }

  // epilogue: C/D layout col=lane&15, row=(lane>>4)*4+reg
#pragma unroll
  for (int ai = 0; ai < 4; ++ai) {
#pragma unroll
    for (int rr = 0; rr < 4; ++rr) {
      int rowl = wr * 64 + ai * 16 + ((l >> 4) << 2) + rr;
      int p = t0 + rowl;
      if (p < count) {
        size_t off = (size_t)(gb + p) * D;
#pragma unroll
        for (int bj = 0; bj < 8; ++bj) {
          int col = o0 + wc * 128 + bj * 16 + (l & 15);
          EO[off + col] = f2bf(acc[ai][bj][rr]);
        }
      }
    }
  }
}

// ---------------- combine: MOEb[t] = w1*(EO[s1]+b_e1) + w2*(EO[s2]+b_e2)
__global__ __launch_bounds__(256) void combine_kernel(
    const short* __restrict__ EO,
    const int* __restrict__ te1, const int* __restrict__ te2,
    const float* __restrict__ tw1, const float* __restrict__ tw2,
    const int* __restrict__ slot1, const int* __restrict__ slot2,
    const float* __restrict__ exp_b, short* __restrict__ MOEb) {
  int idx = blockIdx.x * 256 + threadIdx.x;   // 6192*96 total
  int t = idx / 96, cg = idx - t * 96;
  int c0 = cg * 8;
  int e1 = te1[t], e2 = te2[t];
  float w1 = tw1[t], w2 = tw2[t];
  short8 a = *(const short8*)(EO + (size_t)slot1[t] * D + c0);
  short8 b = *(const short8*)(EO + (size_t)slot2[t] * D + c0);
  const float* b1 = exp_b + e1 * D + c0;
  const float* b2 = exp_b + e2 * D + c0;
  short8 o;
#pragma unroll
  for (int j = 0; j < 8; ++j)
    o[j] = f2bf(w1 * (bf2f(a[j]) + b1[j]) + w2 * (bf2f(b[j]) + b2[j]));
  *(short8*)(MOEb + (size_t)t * D + c0) = o;
}

// ---------------- QKV projections (MFMA bf16), 128x256 tile
// z=0: Q (32 tb), z=1: K (16 tb), z=2: V (16 tb)
__global__ __launch_bounds__(256) void qkv_kernel(
    const short* __restrict__ MOEb, const short* __restrict__ wT,
    const float* __restrict__ bq, const float* __restrict__ bk,
    const float* __restrict__ bv,
    short* __restrict__ Qb, short* __restrict__ Kb, float* __restrict__ V) {
  int z = blockIdx.z;
  int tb = blockIdx.x;
  if (z > 0 && tb >= 16) return;
  int o0 = blockIdx.y * 256;
  int base = (z == 0) ? 0 : MEN_TOK0;
  const short* W = wT + (size_t)z * D * D;
  const float* bias = (z == 0) ? bq : (z == 1) ? bk : bv;
  // rows tb*128 .. tb*128+127 map to MOEb rows base + tb*129 + 1 + (0..127)
  const short* Ag = MOEb + (size_t)(base + tb * 129 + 1) * D;

  __shared__ short8 As[1024];
  __shared__ short8 Bs[2048];
  int tid = threadIdx.x;
  int l = tid & 63, w = tid >> 6;
  int wr = w >> 1, wc = w & 1;

  floatx4 acc[4][8];
#pragma unroll
  for (int ai = 0; ai < 4; ++ai)
#pragma unroll
    for (int bj = 0; bj < 8; ++bj) acc[ai][bj] = (floatx4){0.f, 0.f, 0.f, 0.f};

  for (int k0 = 0; k0 < D; k0 += 64) {
    __syncthreads();
#pragma unroll
    for (int q = 0; q < 4; ++q) {
      int p = q * 256 + tid;
      int row = p >> 3, c = p & 7;
      As[(row << 3) + (c ^ (row & 7))] =
          *(const short8*)(Ag + (size_t)row * D + k0 + c * 8);
    }
#pragma unroll
    for (int q = 0; q < 8; ++q) {
      int p = q * 256 + tid;
      int row = p >> 3, c = p & 7;
      Bs[(row << 3) + (c ^ (row & 7))] =
          *(const short8*)(W + (size_t)(o0 + row) * D + k0 + c * 8);
    }
    __syncthreads();
#pragma unroll
    for (int kk = 0; kk < 2; ++kk) {
      int kc = kk * 4 + (l >> 4);
      short8 a[4], bb[8];
#pragma unroll
      for (int ai = 0; ai < 4; ++ai) {
        int ar = wr * 64 + ai * 16 + (l & 15);
        a[ai] = As[(ar << 3) + (kc ^ (ar & 7))];
      }
#pragma unroll
      for (int bj = 0; bj < 8; ++bj) {
        int br = wc * 128 + bj * 16 + (l & 15);
        bb[bj] = Bs[(br << 3) + (kc ^ (br & 7))];
      }
#pragma unroll
      for (int ai = 0; ai < 4; ++ai)
#pragma unroll
        for (int bj = 0; bj < 8; ++bj)
          acc[ai][bj] = __builtin_amdgcn_mfma_f32_16x16x32_bf16(a[ai], bb[bj], acc[ai][bj], 0, 0, 0);
    }
  }

#pragma unroll
  for (int ai = 0; ai < 4; ++ai) {
#pragma unroll
    for (int rr = 0; rr < 4; ++rr) {
      int rowl = wr * 64 + ai * 16 + ((l >> 4) << 2) + rr;
      size_t rglob = (size_t)tb * 128 + rowl;
#pragma unroll
      for (int bj = 0; bj < 8; ++bj) {
        int col = o0 + wc * 128 + bj * 16 + (l & 15);
        float v = acc[ai][bj][rr] + bias[col];
        if (z == 0)      Qb[rglob * D + col] = f2bf(v);
        else if (z == 1) Kb[rglob * D + col] = f2bf(v);
        else             V [rglob * D + col] = v;
      }
    }
  }
}

// ---------------- fused scores GEMM (MFMA) + in-register softmax + column-mean
__global__ __launch_bounds__(256) void attn_kernel(
    const short* __restrict__ Qb, const short* __restrict__ Kb,
    float* __restrict__ pbar_ws) {
  int b = blockIdx.x, n = blockIdx.y;
  __shared__ short8 Qs[1024];   // 128 rows x 8 chunks, swizzled
  __shared__ short8 Ks[1024];
  __shared__ float pb[128];
  int tid = threadIdx.x;
  int l = tid & 63, w = tid >> 6;
  if (tid < 128) pb[tid] = 0.f;

  floatx4 acc[2][8];
#pragma unroll
  for (int i = 0; i < 2; ++i)
#pragma unroll
    for (int j = 0; j < 8; ++j) acc[i][j] = (floatx4){0.f, 0.f, 0.f, 0.f};

  const short* qg = Qb + (size_t)n * 128 * D;
  const short* kg = Kb + (size_t)b * 128 * D;

  for (int k0 = 0; k0 < D; k0 += 64) {
    __syncthreads();
#pragma unroll
    for (int q = 0; q < 4; ++q) {
      int p = q * 256 + tid;
      int row = p >> 3, c = p & 7;
      int sw = (row << 3) + (c ^ (row & 7));
      Qs[sw] = *(const short8*)(qg + (size_t)row * D + k0 + c * 8);
      Ks[sw] = *(const short8*)(kg + (size_t)row * D + k0 + c * 8);
    }
    __syncthreads();
#pragma unroll
    for (int kk = 0; kk < 2; ++kk) {
      int kc = kk * 4 + (l >> 4);
      short8 a[2], bb[8];
#pragma unroll
      for (int i = 0; i < 2; ++i) {
        int ar = w * 32 + i * 16 + (l & 15);
        a[i] = Qs[(ar << 3) + (kc ^ (ar & 7))];
      }
#pragma unroll
      for (int j = 0; j < 8; ++j) {
        int br = j * 16 + (l & 15);
        bb[j] = Ks[(br << 3) + (kc ^ (br & 7))];
      }
#pragma unroll
      for (int i = 0; i < 2; ++i)
#pragma unroll
        for (int j = 0; j < 8; ++j)
          acc[i][j] = __builtin_amdgcn_mfma_f32_16x16x32_bf16(a[i], bb[j], acc[i][j], 0, 0, 0);
    }
  }

  const float scale = 0.03608439182435161f; // 1/sqrt(768)
  float colsum[8];
#pragma unroll
  for (int j = 0; j < 8; ++j) colsum[j] = 0.f;

#pragma unroll
  for (int i = 0; i < 2; ++i) {
#pragma unroll
    for (int r = 0; r < 4; ++r) {
      float mx = -3.0e38f;
#pragma unroll
      for (int j = 0; j < 8; ++j) mx = fmaxf(mx, acc[i][j][r]);
      mx = fmaxf(mx, __shfl_xor(mx, 1));
      mx = fmaxf(mx, __shfl_xor(mx, 2));
      mx = fmaxf(mx, __shfl_xor(mx, 4));
      mx = fmaxf(mx, __shfl_xor(mx, 8));
      float pv[8], sm = 0.f;
#pragma unroll
      for (int j = 0; j < 8; ++j) { pv[j] = __expf((acc[i][j][r] - mx) * scale); sm += pv[j]; }
      sm += __shfl_xor(sm, 1);
      sm += __shfl_xor(sm, 2);
      sm += __shfl_xor(sm, 4);
      sm += __shfl_xor(sm, 8);
      float inv = 1.f / sm;
#pragma unroll
      for (int j = 0; j < 8; ++j) colsum[j] += pv[j] * inv;
    }
  }
#pragma unroll
  for (int j = 0; j < 8; ++j) {
    colsum[j] += __shfl_xor(colsum[j], 16);
    colsum[j] += __shfl_xor(colsum[j], 32);
  }
  if (l < 16) {
#pragma unroll
    for (int j = 0; j < 8; ++j) atomicAdd(&pb[j * 16 + l], colsum[j]);
  }
  __syncthreads();
  if (tid < 128) pbar_ws[((size_t)n * 16 + b) * 128 + tid] = pb[tid] * (1.f / 128.f);
}

// ---------------- ctx[b,n,d] = sum_m pbar[n,b,m] * V[b,m,d]  (V read once)
__global__ __launch_bounds__(256) void pv_kernel(
    const float* __restrict__ pbar_ws, const float* __restrict__ V,
    float* __restrict__ CTX) {
  int b = blockIdx.x, dc = blockIdx.y;
  __shared__ float pbs[4096];   // [n][m]
  int tid = threadIdx.x;
#pragma unroll
  for (int i = 0; i < 16; ++i) {
    int idx = i * 256 + tid;
    int nn = idx >> 7, m = idx & 127;
    pbs[idx] = pbar_ws[((size_t)nn * 16 + b) * 128 + m];
  }
  __syncthreads();
  int d = dc * 256 + tid;
  float acc[32];
#pragma unroll
  for (int nn = 0; nn < 32; ++nn) acc[nn] = 0.f;
  const float* vb = V + (size_t)b * 128 * D + d;
  for (int m = 0; m < 128; ++m) {
    float v = vb[(size_t)m * D];
#pragma unroll
    for (int nn = 0; nn < 32; ++nn) acc[nn] += pbs[nn * 128 + m] * v;
  }
#pragma unroll
  for (int nn = 0; nn < 32; ++nn) CTX[((size_t)b * 32 + nn) * D + d] = acc[nn];
}

__device__ __forceinline__ float blockSum(float v, volatile float* red, int tid) {
#pragma unroll
  for (int off = 32; off > 0; off >>= 1) v += __shfl_down(v, off);
  __syncthreads();
  if ((tid & 63) == 0) red[tid >> 6] = v;
  __syncthreads();
  return red[0] + red[1] + red[2] + red[3];
}

// ---------------- LayerNorm + final dots
__global__ __launch_bounds__(256) void ln_dot_kernel(
    const float* __restrict__ CTX, const short* __restrict__ MOEb,
    const float* __restrict__ ecls, const float* __restrict__ mcls,
    const float* __restrict__ ln_w, const float* __restrict__ ln_b,
    float* __restrict__ out) {
  __shared__ float red[4];
  int bn = blockIdx.x;
  int b = bn >> 5, n = bn & 31;
  int tid = threadIdx.x;
  const float* cr = CTX + (size_t)bn * D;
  float ctx[3];
#pragma unroll
  for (int r = 0; r < 3; ++r) ctx[r] = cr[tid + r * 256];
  float mu = blockSum(ctx[0] + ctx[1] + ctx[2], red, tid) * (1.f / 768.f);
  float vs = 0.f;
#pragma unroll
  for (int r = 0; r < 3; ++r) { float c = ctx[r] - mu; vs += c * c; }
  float var = blockSum(vs, red, tid) * (1.f / 768.f);
  float rstd = rsqrtf(var + 1e-5f);
  const short* em = MOEb + (size_t)(n * 129) * D;
  float g2l_p = 0.f, g2g_p = 0.f;
#pragma unroll
  for (int r = 0; r < 3; ++r) {
    int d = tid + r * 256;
    float cl = (ctx[r] - mu) * rstd * ln_w[d] + ln_b[d];
    g2l_p += bf2f(em[d]) * cl;
    g2g_p += mcls[(size_t)b * D + d] * ecls[(size_t)n * D + d];
  }
  float g2l = blockSum(g2l_p, red, tid);
  float g2g = blockSum(g2g_p, red, tid);
  if (tid == 0) out[bn] = 0.5f * (g2l + g2g);
}

extern "C" void kernel_launch(void* const* d_in, const int* in_sizes, int n_in,
                              void* d_out, int out_size, void* d_ws, size_t ws_size,
                              hipStream_t stream) {
  const float* ecls   = (const float*)d_in[0];
  const float* etok   = (const float*)d_in[1];
  const float* mcls   = (const float*)d_in[2];
  const float* mtok   = (const float*)d_in[3];
  const float* gate_w = (const float*)d_in[4];
  const float* gate_b = (const float*)d_in[5];
  const float* exp_w  = (const float*)d_in[6];
  const float* exp_b  = (const float*)d_in[7];
  const float* wq     = (const float*)d_in[8];
  const float* bq     = (const float*)d_in[9];
  const float* wk     = (const float*)d_in[10];
  const float* bk     = (const float*)d_in[11];
  const float* wv     = (const float*)d_in[12];
  const float* bv     = (const float*)d_in[13];
  const float* ln_w   = (const float*)d_in[14];
  const float* ln_b   = (const float*)d_in[15];
  float* outp = (float*)d_out;

  char* ws = (char*)d_ws;
  // region A: EO (19,021,824 B) -> later reused for Qb/Kb/V
  short* EO    = (short*)(ws + 0);
  short* Qb    = (short*)(ws + 0);              //  6,291,456 B
  short* Kb    = (short*)(ws + 6291456);        //  3,145,728 B
  float* V     = (float*)(ws + 9437184);        //  6,291,456 B (ends 15,728,640)
  // region B: Xb (gate output, bf16 tokens) aliases MOEb (combine output) —
  // Xb is dead before combine writes MOEb (stream-ordered).
  short* Xb    = (short*)(ws + 19021824);       //  9,510,912 B
  short* MOEb  = (short*)(ws + 19021824);
  short* expwT = (short*)(ws + 28532736);       //  9,437,184 B
  short* wT    = (short*)(ws + 37969920);       //  3,538,944 B
  float* PBAR  = (float*)(ws + 41508864);       //    262,144 B
  float* CTX   = (float*)(ws + 41771008);       //  1,572,864 B (ends 43,343,872)
  int*   te1   = (int*)  (ws + 43343872);       //     24,768 B
  int*   te2   = (int*)  (ws + 43368640);
  float* tw1   = (float*)(ws + 43393408);
  float* tw2   = (float*)(ws + 43418176);
  int*   slot1 = (int*)  (ws + 43442944);
  int*   slot2 = (int*)  (ws + 43467712);
  int*   lst_tok  = (int*)(ws + 43492480);      //     49,536 B
  int*   localcnt = (int*)(ws + 43542016);      //        800 B
  int*   cnt   = (int*)  (ws + 43542816);       //         32 B
  int*   basee = (int*)  (ws + 43542848);       //         32 B  (total 43,542,880)

  gate_kernel<<<NTOK / 4, 256, 0, stream>>>(ecls, etok, mcls, mtok, gate_w, gate_b,
                                            te1, te2, tw1, tw2, Xb);
  count_kernel<<<NCBLK, 256, 0, stream>>>(te1, te2, localcnt);
  compact_kernel<<<NCBLK, 256, 0, stream>>>(te1, te2, localcnt, lst_tok, slot1, slot2,
                                            cnt, basee);
  tcvt_kernel<<<dim3(12, 12, 11), 256, 0, stream>>>(exp_w, wq, wk, wv, expwT, wT);
  moe_kernel<<<49 * 3 * 8, 256, 0, stream>>>(Xb, expwT, cnt, basee, lst_tok, EO);
  combine_kernel<<<2322, 256, 0, stream>>>(EO, te1, te2, tw1, tw2, slot1, slot2,
                                           exp_b, MOEb);
  qkv_kernel<<<dim3(32, 3, 3), 256, 0, stream>>>(MOEb, wT, bq, bk, bv, Qb, Kb, V);
  attn_kernel<<<dim3(16, 32), 256, 0, stream>>>(Qb, Kb, PBAR);
  pv_kernel<<<dim3(16, 3), 256, 0, stream>>>(PBAR, V, CTX);
  ln_dot_kernel<<<512, 256, 0, stream>>>(CTX, MOEb, ecls, mcls, ln_w, ln_b, outp);
}

// Round 5
// 152.889 us; speedup vs baseline: 1.4155x; 1.4155x over previous
//
#include <hip/hip_runtime.h>
#include <math.h>

#define D 768
#define NE 8
#define NTOK 6192      // 32*129 + 16*129
#define MEN_TOK0 4128  // 32*129

typedef __attribute__((ext_vector_type(8))) short short8;   // 8 x bf16
typedef __attribute__((ext_vector_type(4))) short short4b;  // 4 x bf16
typedef __attribute__((ext_vector_type(4))) float floatx4;  // MFMA C/D

__device__ __forceinline__ short f2bf(float f) {
  union { float f; unsigned u; } x; x.f = f;
  unsigned r = x.u + 0x7fffu + ((x.u >> 16) & 1u);
  return (short)(r >> 16);
}
__device__ __forceinline__ float bf2f(short s) {
  union { unsigned u; float f; } x; x.u = ((unsigned)(unsigned short)s) << 16;
  return x.f;
}

// Map concatenated token index -> source row pointer (virtual concat, no copy).
__device__ __forceinline__ const float* token_row(int t,
    const float* __restrict__ ecls, const float* __restrict__ etok,
    const float* __restrict__ mcls, const float* __restrict__ mtok) {
  if (t < MEN_TOK0) {
    int n = t / 129, s = t - n * 129;
    return (s == 0) ? (ecls + n * D) : (etok + (size_t)(n * 128 + s - 1) * D);
  } else {
    int tm = t - MEN_TOK0;
    int b = tm / 129, s = tm - b * 129;
    return (s == 0) ? (mcls + b * D) : (mtok + (size_t)(b * 128 + s - 1) * D);
  }
}

// ---------------- prep: fused gate (blocks 0..1547) + weight transpose/cvt
// gate: logits top-2 + bf16 token materialization (Xb). tcvt: exp_w/wq/wk/wv -> (o,k) bf16
__global__ __launch_bounds__(256) void prep_kernel(
    const float* __restrict__ ecls, const float* __restrict__ etok,
    const float* __restrict__ mcls, const float* __restrict__ mtok,
    const float* __restrict__ gate_w, const float* __restrict__ gate_b,
    const float* __restrict__ exp_w, const float* __restrict__ wq,
    const float* __restrict__ wk, const float* __restrict__ wv,
    int* __restrict__ te1, int* __restrict__ te2,
    float* __restrict__ tw1, float* __restrict__ tw2,
    short* __restrict__ Xb, short* __restrict__ expwT, short* __restrict__ wT) {
  __shared__ float tbuf[64][65];
  int bid = blockIdx.x;
  int tid = threadIdx.x;
  if (bid < 1548) {
    // ---- gate part
    int t = bid * 4 + (tid >> 6);
    int lane = tid & 63;
    const float* xr = token_row(t, ecls, etok, mcls, mtok);
    float acc[NE];
#pragma unroll
    for (int e = 0; e < NE; ++e) acc[e] = 0.f;
#pragma unroll
    for (int it = 0; it < 3; ++it) {
      int d0 = lane * 4 + it * 256;
      floatx4 x = *(const floatx4*)(xr + d0);
      short4b xb;
#pragma unroll
      for (int q = 0; q < 4; ++q) {
        xb[q] = f2bf(x[q]);
        float xv = x[q];
#pragma unroll
        for (int e = 0; e < NE; ++e) acc[e] += xv * gate_w[(d0 + q) * NE + e];
      }
      *(short4b*)(Xb + (size_t)t * D + d0) = xb;
    }
#pragma unroll
    for (int e = 0; e < NE; ++e) {
#pragma unroll
      for (int off = 32; off > 0; off >>= 1) acc[e] += __shfl_down(acc[e], off);
    }
    if (lane == 0) {
      float lg[NE];
#pragma unroll
      for (int e = 0; e < NE; ++e) lg[e] = acc[e] + gate_b[e];
      int e1 = 0;
#pragma unroll
      for (int e = 1; e < NE; ++e) if (lg[e] > lg[e1]) e1 = e;
      int e2 = (e1 == 0) ? 1 : 0;
#pragma unroll
      for (int e = 0; e < NE; ++e) {
        if (e != e1 && lg[e] > lg[e2]) e2 = e;
      }
      float w1 = 1.f / (1.f + __expf(lg[e2] - lg[e1]));
      te1[t] = e1; te2[t] = e2;
      tw1[t] = w1; tw2[t] = 1.f - w1;
    }
  } else {
    // ---- tcvt part
    int zz = bid - 1548;
    int z = zz / 144, rem = zz % 144;
    int k0 = (rem / 12) * 64, o0 = (rem % 12) * 64;
    const float* src; short* dst;
    if (z < 8) { src = exp_w + (size_t)z * D * D; dst = expwT + (size_t)z * D * D; }
    else { src = (z == 8) ? wq : (z == 9) ? wk : wv; dst = wT + (size_t)(z - 8) * D * D; }
    int tx = tid & 63, ty = tid >> 6;
#pragma unroll
    for (int i = 0; i < 16; ++i) {
      int k = i * 4 + ty;
      tbuf[k][tx] = src[(size_t)(k0 + k) * D + o0 + tx];
    }
    __syncthreads();
#pragma unroll
    for (int i = 0; i < 16; ++i) {
      int o = i * 4 + ty;
      dst[(size_t)(o0 + o) * D + k0 + tx] = f2bf(tbuf[tx][o]);
    }
  }
}

// ---------------- route: fused histogram + compaction (single block, LDS atomics)
__global__ __launch_bounds__(1024) void route_kernel(
    const int* __restrict__ te1, const int* __restrict__ te2,
    int* __restrict__ lst_tok, int* __restrict__ slot1, int* __restrict__ slot2,
    int* __restrict__ cnt, int* __restrict__ basee) {
  __shared__ int hist[NE];
  __shared__ int base_s[NE];
  int tid = threadIdx.x;
  if (tid < NE) hist[tid] = 0;
  __syncthreads();
  for (int t = tid; t < NTOK; t += 1024) {
    atomicAdd(&hist[te1[t]], 1);
    atomicAdd(&hist[te2[t]], 1);
  }
  __syncthreads();
  if (tid == 0) {
    int acc = 0;
    for (int e = 0; e < NE; ++e) {
      base_s[e] = acc;
      cnt[e] = hist[e];
      basee[e] = acc;
      acc += hist[e];
    }
  }
  __syncthreads();
  if (tid < NE) hist[tid] = 0;   // reuse as running rank counters
  __syncthreads();
  for (int t = tid; t < NTOK; t += 1024) {
    int e1 = te1[t], e2 = te2[t];
    int r1 = atomicAdd(&hist[e1], 1);
    int r2 = atomicAdd(&hist[e2], 1);
    int s1 = base_s[e1] + r1;
    int s2 = base_s[e2] + r2;
    slot1[t] = s1; slot2[t] = s2;
    lst_tok[s1] = t; lst_tok[s2] = t;
  }
}

// ---------------- grouped expert GEMM (MFMA bf16), 128x128 tile, 2x2 waves
// flattened grid: e = id&7 (XCD pinning), r = id>>3: ob = r%6, tb = r/6
__global__ __launch_bounds__(256) void moe_kernel(
    const short* __restrict__ Xb, const short* __restrict__ expwT,
    const int* __restrict__ cnt, const int* __restrict__ basee,
    const int* __restrict__ lst_tok, short* __restrict__ EO) {
  int id = blockIdx.x;
  int e = id & 7;
  int r = id >> 3;
  int ob = r % 6;
  int tb = r / 6;           // 0..48
  int count = cnt[e];
  int t0 = tb * 128;
  if (t0 >= count) return;
  int o0 = ob * 128;
  int gb = basee[e];

  __shared__ short8 As[1024];   // 128 rows x 8 chunks, XOR-swizzled
  __shared__ short8 Bs[1024];   // 128 rows x 8 chunks
  __shared__ int stok[128];

  int tid = threadIdx.x;
  int l = tid & 63, w = tid >> 6;
  int wr = w >> 1, wc = w & 1;

  if (tid < 128) {
    int p = t0 + tid;
    stok[tid] = lst_tok[gb + (p < count ? p : 0)];
  }

  floatx4 acc[4][4];
#pragma unroll
  for (int ai = 0; ai < 4; ++ai)
#pragma unroll
    for (int bj = 0; bj < 4; ++bj) acc[ai][bj] = (floatx4){0.f, 0.f, 0.f, 0.f};

  const short* Bg = expwT + (size_t)e * D * D;

  for (int k0 = 0; k0 < D; k0 += 64) {
    __syncthreads();
#pragma unroll
    for (int q = 0; q < 4; ++q) {
      int p = q * 256 + tid;
      int row = p >> 3, c = p & 7;
      int sw = (row << 3) + (c ^ (row & 7));
      As[sw] = *(const short8*)(Xb + (size_t)stok[row] * D + k0 + c * 8);
      Bs[sw] = *(const short8*)(Bg + (size_t)(o0 + row) * D + k0 + c * 8);
    }
    __syncthreads();
#pragma unroll
    for (int kk = 0; kk < 2; ++kk) {
      int kc = kk * 4 + (l >> 4);
      short8 a[4], bb[4];
#pragma unroll
      for (int ai = 0; ai < 4; ++ai) {
        int ar = wr * 64 + ai * 16 + (l & 15);
        a[ai] = As[(ar << 3) + (kc ^ (ar & 7))];
      }
#pragma unroll
      for (int bj = 0; bj < 4; ++bj) {
        int br = wc * 64 + bj * 16 + (l & 15);
        bb[bj] = Bs[(br << 3) + (kc ^ (br & 7))];
      }
#pragma unroll
      for (int ai = 0; ai < 4; ++ai)
#pragma unroll
        for (int bj = 0; bj < 4; ++bj)
          acc[ai][bj] = __builtin_amdgcn_mfma_f32_16x16x32_bf16(a[ai], bb[bj], acc[ai][bj], 0, 0, 0);
    }
  }

  // epilogue: C/D layout col=lane&15, row=(lane>>4)*4+reg
#pragma unroll
  for (int ai = 0; ai < 4; ++ai) {
#pragma unroll
    for (int rr = 0; rr < 4; ++rr) {
      int rowl = wr * 64 + ai * 16 + ((l >> 4) << 2) + rr;
      int p = t0 + rowl;
      if (p < count) {
        size_t off = (size_t)(gb + p) * D;
#pragma unroll
        for (int bj = 0; bj < 4; ++bj) {
          int col = o0 + wc * 64 + bj * 16 + (l & 15);
          EO[off + col] = f2bf(acc[ai][bj][rr]);
        }
      }
    }
  }
}

// ---------------- combine: MOEb[t] = w1*(EO[s1]+b_e1) + w2*(EO[s2]+b_e2)
__global__ __launch_bounds__(256) void combine_kernel(
    const short* __restrict__ EO,
    const int* __restrict__ te1, const int* __restrict__ te2,
    const float* __restrict__ tw1, const float* __restrict__ tw2,
    const int* __restrict__ slot1, const int* __restrict__ slot2,
    const float* __restrict__ exp_b, short* __restrict__ MOEb) {
  int idx = blockIdx.x * 256 + threadIdx.x;   // 6192*96 total
  int t = idx / 96, cg = idx - t * 96;
  int c0 = cg * 8;
  int e1 = te1[t], e2 = te2[t];
  float w1 = tw1[t], w2 = tw2[t];
  short8 a = *(const short8*)(EO + (size_t)slot1[t] * D + c0);
  short8 b = *(const short8*)(EO + (size_t)slot2[t] * D + c0);
  const float* b1 = exp_b + e1 * D + c0;
  const float* b2 = exp_b + e2 * D + c0;
  short8 o;
#pragma unroll
  for (int j = 0; j < 8; ++j)
    o[j] = f2bf(w1 * (bf2f(a[j]) + b1[j]) + w2 * (bf2f(b[j]) + b2[j]));
  *(short8*)(MOEb + (size_t)t * D + c0) = o;
}

// ---------------- QKV projections (MFMA bf16), 64x128 tile, 2x2 waves of 32x64
// flattened grid: id<384: z=0 (Q, 64 tb); id<576: z=1 (K); else z=2 (V). r: tb=r/6, ob=r%6
__global__ __launch_bounds__(256) void qkv_kernel(
    const short* __restrict__ MOEb, const short* __restrict__ wT,
    const float* __restrict__ bq, const float* __restrict__ bk,
    const float* __restrict__ bv,
    short* __restrict__ Qb, short* __restrict__ Kb, float* __restrict__ V) {
  int id = blockIdx.x;
  int z, r;
  if (id < 384)      { z = 0; r = id; }
  else if (id < 576) { z = 1; r = id - 384; }
  else               { z = 2; r = id - 576; }
  int tb = r / 6, ob = r % 6;
  int o0 = ob * 128;
  int base = (z == 0) ? 0 : MEN_TOK0;
  const short* W = wT + (size_t)z * D * D;
  const float* bias = (z == 0) ? bq : (z == 1) ? bk : bv;
  // 64-row tile never straddles a 129-slab: slab = tb>>1, offset (tb&1)*64
  const short* Ag = MOEb + (size_t)(base + (tb >> 1) * 129 + 1 + (tb & 1) * 64) * D;

  __shared__ short8 As[512];    // 64 rows x 8 chunks
  __shared__ short8 Bs[1024];   // 128 rows x 8 chunks
  int tid = threadIdx.x;
  int l = tid & 63, w = tid >> 6;
  int wr = w >> 1, wc = w & 1;

  floatx4 acc[2][4];
#pragma unroll
  for (int ai = 0; ai < 2; ++ai)
#pragma unroll
    for (int bj = 0; bj < 4; ++bj) acc[ai][bj] = (floatx4){0.f, 0.f, 0.f, 0.f};

  for (int k0 = 0; k0 < D; k0 += 64) {
    __syncthreads();
#pragma unroll
    for (int q = 0; q < 2; ++q) {
      int p = q * 256 + tid;
      int row = p >> 3, c = p & 7;
      As[(row << 3) + (c ^ (row & 7))] =
          *(const short8*)(Ag + (size_t)row * D + k0 + c * 8);
    }
#pragma unroll
    for (int q = 0; q < 4; ++q) {
      int p = q * 256 + tid;
      int row = p >> 3, c = p & 7;
      Bs[(row << 3) + (c ^ (row & 7))] =
          *(const short8*)(W + (size_t)(o0 + row) * D + k0 + c * 8);
    }
    __syncthreads();
#pragma unroll
    for (int kk = 0; kk < 2; ++kk) {
      int kc = kk * 4 + (l >> 4);
      short8 a[2], bb[4];
#pragma unroll
      for (int ai = 0; ai < 2; ++ai) {
        int ar = wr * 32 + ai * 16 + (l & 15);
        a[ai] = As[(ar << 3) + (kc ^ (ar & 7))];
      }
#pragma unroll
      for (int bj = 0; bj < 4; ++bj) {
        int br = wc * 64 + bj * 16 + (l & 15);
        bb[bj] = Bs[(br << 3) + (kc ^ (br & 7))];
      }
#pragma unroll
      for (int ai = 0; ai < 2; ++ai)
#pragma unroll
        for (int bj = 0; bj < 4; ++bj)
          acc[ai][bj] = __builtin_amdgcn_mfma_f32_16x16x32_bf16(a[ai], bb[bj], acc[ai][bj], 0, 0, 0);
    }
  }

#pragma unroll
  for (int ai = 0; ai < 2; ++ai) {
#pragma unroll
    for (int rr = 0; rr < 4; ++rr) {
      int rowl = wr * 32 + ai * 16 + ((l >> 4) << 2) + rr;
      size_t rglob = (size_t)tb * 64 + rowl;
#pragma unroll
      for (int bj = 0; bj < 4; ++bj) {
        int col = o0 + wc * 64 + bj * 16 + (l & 15);
        float v = acc[ai][bj][rr] + bias[col];
        if (z == 0)      Qb[rglob * D + col] = f2bf(v);
        else if (z == 1) Kb[rglob * D + col] = f2bf(v);
        else             V [rglob * D + col] = v;
      }
    }
  }
}

// ---------------- fused scores GEMM (MFMA) + in-register softmax + column-mean
// flattened grid: id = b*32 + n  (XCD = n%8 -> K panels L2-resident per XCD)
__global__ __launch_bounds__(256) void attn_kernel(
    const short* __restrict__ Qb, const short* __restrict__ Kb,
    float* __restrict__ pbar_ws) {
  int id = blockIdx.x;
  int n = id & 31, b = id >> 5;
  __shared__ short8 Qs[1024];   // 128 rows x 8 chunks, swizzled
  __shared__ short8 Ks[1024];
  __shared__ float pb[128];
  int tid = threadIdx.x;
  int l = tid & 63, w = tid >> 6;
  if (tid < 128) pb[tid] = 0.f;

  floatx4 acc[2][8];
#pragma unroll
  for (int i = 0; i < 2; ++i)
#pragma unroll
    for (int j = 0; j < 8; ++j) acc[i][j] = (floatx4){0.f, 0.f, 0.f, 0.f};

  const short* qg = Qb + (size_t)n * 128 * D;
  const short* kg = Kb + (size_t)b * 128 * D;

  for (int k0 = 0; k0 < D; k0 += 64) {
    __syncthreads();
#pragma unroll
    for (int q = 0; q < 4; ++q) {
      int p = q * 256 + tid;
      int row = p >> 3, c = p & 7;
      int sw = (row << 3) + (c ^ (row & 7));
      Qs[sw] = *(const short8*)(qg + (size_t)row * D + k0 + c * 8);
      Ks[sw] = *(const short8*)(kg + (size_t)row * D + k0 + c * 8);
    }
    __syncthreads();
#pragma unroll
    for (int kk = 0; kk < 2; ++kk) {
      int kc = kk * 4 + (l >> 4);
      short8 a[2], bb[8];
#pragma unroll
      for (int i = 0; i < 2; ++i) {
        int ar = w * 32 + i * 16 + (l & 15);
        a[i] = Qs[(ar << 3) + (kc ^ (ar & 7))];
      }
#pragma unroll
      for (int j = 0; j < 8; ++j) {
        int br = j * 16 + (l & 15);
        bb[j] = Ks[(br << 3) + (kc ^ (br & 7))];
      }
#pragma unroll
      for (int i = 0; i < 2; ++i)
#pragma unroll
        for (int j = 0; j < 8; ++j)
          acc[i][j] = __builtin_amdgcn_mfma_f32_16x16x32_bf16(a[i], bb[j], acc[i][j], 0, 0, 0);
    }
  }

  const float scale = 0.03608439182435161f; // 1/sqrt(768)
  float colsum[8];
#pragma unroll
  for (int j = 0; j < 8; ++j) colsum[j] = 0.f;

#pragma unroll
  for (int i = 0; i < 2; ++i) {
#pragma unroll
    for (int r = 0; r < 4; ++r) {
      float mx = -3.0e38f;
#pragma unroll
      for (int j = 0; j < 8; ++j) mx = fmaxf(mx, acc[i][j][r]);
      mx = fmaxf(mx, __shfl_xor(mx, 1));
      mx = fmaxf(mx, __shfl_xor(mx, 2));
      mx = fmaxf(mx, __shfl_xor(mx, 4));
      mx = fmaxf(mx, __shfl_xor(mx, 8));
      float pv[8], sm = 0.f;
#pragma unroll
      for (int j = 0; j < 8; ++j) { pv[j] = __expf((acc[i][j][r] - mx) * scale); sm += pv[j]; }
      sm += __shfl_xor(sm, 1);
      sm += __shfl_xor(sm, 2);
      sm += __shfl_xor(sm, 4);
      sm += __shfl_xor(sm, 8);
      float inv = 1.f / sm;
#pragma unroll
      for (int j = 0; j < 8; ++j) colsum[j] += pv[j] * inv;
    }
  }
#pragma unroll
  for (int j = 0; j < 8; ++j) {
    colsum[j] += __shfl_xor(colsum[j], 16);
    colsum[j] += __shfl_xor(colsum[j], 32);
  }
  if (l < 16) {
#pragma unroll
    for (int j = 0; j < 8; ++j) atomicAdd(&pb[j * 16 + l], colsum[j]);
  }
  __syncthreads();
  if (tid < 128) pbar_ws[((size_t)n * 16 + b) * 128 + tid] = pb[tid] * (1.f / 128.f);
}

// ---------------- ctx[b,n,d] = sum_m pbar[n,b,m] * V[b,m,d]  (V read once)
__global__ __launch_bounds__(256) void pv_kernel(
    const float* __restrict__ pbar_ws, const float* __restrict__ V,
    float* __restrict__ CTX) {
  int b = blockIdx.x, dc = blockIdx.y;
  __shared__ float pbs[4096];   // [n][m]
  int tid = threadIdx.x;
#pragma unroll
  for (int i = 0; i < 16; ++i) {
    int idx = i * 256 + tid;
    int nn = idx >> 7, m = idx & 127;
    pbs[idx] = pbar_ws[((size_t)nn * 16 + b) * 128 + m];
  }
  __syncthreads();
  int d = dc * 256 + tid;
  float acc[32];
#pragma unroll
  for (int nn = 0; nn < 32; ++nn) acc[nn] = 0.f;
  const float* vb = V + (size_t)b * 128 * D + d;
  for (int m = 0; m < 128; ++m) {
    float v = vb[(size_t)m * D];
#pragma unroll
    for (int nn = 0; nn < 32; ++nn) acc[nn] += pbs[nn * 128 + m] * v;
  }
#pragma unroll
  for (int nn = 0; nn < 32; ++nn) CTX[((size_t)b * 32 + nn) * D + d] = acc[nn];
}

__device__ __forceinline__ float blockSum(float v, volatile float* red, int tid) {
#pragma unroll
  for (int off = 32; off > 0; off >>= 1) v += __shfl_down(v, off);
  __syncthreads();
  if ((tid & 63) == 0) red[tid >> 6] = v;
  __syncthreads();
  return red[0] + red[1] + red[2] + red[3];
}

// ---------------- LayerNorm + final dots
__global__ __launch_bounds__(256) void ln_dot_kernel(
    const float* __restrict__ CTX, const short* __restrict__ MOEb,
    const float* __restrict__ ecls, const float* __restrict__ mcls,
    const float* __restrict__ ln_w, const float* __restrict__ ln_b,
    float* __restrict__ out) {
  __shared__ float red[4];
  int bn = blockIdx.x;
  int b = bn >> 5, n = bn & 31;
  int tid = threadIdx.x;
  const float* cr = CTX + (size_t)bn * D;
  float ctx[3];
#pragma unroll
  for (int r = 0; r < 3; ++r) ctx[r] = cr[tid + r * 256];
  float mu = blockSum(ctx[0] + ctx[1] + ctx[2], red, tid) * (1.f / 768.f);
  float vs = 0.f;
#pragma unroll
  for (int r = 0; r < 3; ++r) { float c = ctx[r] - mu; vs += c * c; }
  float var = blockSum(vs, red, tid) * (1.f / 768.f);
  float rstd = rsqrtf(var + 1e-5f);
  const short* em = MOEb + (size_t)(n * 129) * D;
  float g2l_p = 0.f, g2g_p = 0.f;
#pragma unroll
  for (int r = 0; r < 3; ++r) {
    int d = tid + r * 256;
    float cl = (ctx[r] - mu) * rstd * ln_w[d] + ln_b[d];
    g2l_p += bf2f(em[d]) * cl;
    g2g_p += mcls[(size_t)b * D + d] * ecls[(size_t)n * D + d];
  }
  float g2l = blockSum(g2l_p, red, tid);
  float g2g = blockSum(g2g_p, red, tid);
  if (tid == 0) out[bn] = 0.5f * (g2l + g2g);
}

extern "C" void kernel_launch(void* const* d_in, const int* in_sizes, int n_in,
                              void* d_out, int out_size, void* d_ws, size_t ws_size,
                              hipStream_t stream) {
  const float* ecls   = (const float*)d_in[0];
  const float* etok   = (const float*)d_in[1];
  const float* mcls   = (const float*)d_in[2];
  const float* mtok   = (const float*)d_in[3];
  const float* gate_w = (const float*)d_in[4];
  const float* gate_b = (const float*)d_in[5];
  const float* exp_w  = (const float*)d_in[6];
  const float* exp_b  = (const float*)d_in[7];
  const float* wq     = (const float*)d_in[8];
  const float* bq     = (const float*)d_in[9];
  const float* wk     = (const float*)d_in[10];
  const float* bk     = (const float*)d_in[11];
  const float* wv     = (const float*)d_in[12];
  const float* bv     = (const float*)d_in[13];
  const float* ln_w   = (const float*)d_in[14];
  const float* ln_b   = (const float*)d_in[15];
  float* outp = (float*)d_out;

  char* ws = (char*)d_ws;
  // region A: EO (19,021,824 B) -> later reused for Qb/Kb/V
  short* EO    = (short*)(ws + 0);
  short* Qb    = (short*)(ws + 0);              //  6,291,456 B
  short* Kb    = (short*)(ws + 6291456);        //  3,145,728 B
  float* V     = (float*)(ws + 9437184);        //  6,291,456 B (ends 15,728,640)
  // region B: Xb (gate output, bf16 tokens) aliases MOEb (combine output) —
  // Xb is dead before combine writes MOEb (stream-ordered).
  short* Xb    = (short*)(ws + 19021824);       //  9,510,912 B
  short* MOEb  = (short*)(ws + 19021824);
  short* expwT = (short*)(ws + 28532736);       //  9,437,184 B
  short* wT    = (short*)(ws + 37969920);       //  3,538,944 B
  float* PBAR  = (float*)(ws + 41508864);       //    262,144 B
  float* CTX   = (float*)(ws + 41771008);       //  1,572,864 B (ends 43,343,872)
  int*   te1   = (int*)  (ws + 43343872);       //     24,768 B each
  int*   te2   = (int*)  (ws + 43368640);
  float* tw1   = (float*)(ws + 43393408);
  float* tw2   = (float*)(ws + 43418176);
  int*   slot1 = (int*)  (ws + 43442944);
  int*   slot2 = (int*)  (ws + 43467712);
  int*   lst_tok  = (int*)(ws + 43492480);      //     49,536 B
  int*   cnt   = (int*)  (ws + 43542816);       //         32 B
  int*   basee = (int*)  (ws + 43542848);       //         32 B  (total 43,542,880)

  prep_kernel<<<1548 + 1584, 256, 0, stream>>>(ecls, etok, mcls, mtok, gate_w, gate_b,
                                               exp_w, wq, wk, wv,
                                               te1, te2, tw1, tw2, Xb, expwT, wT);
  route_kernel<<<1, 1024, 0, stream>>>(te1, te2, lst_tok, slot1, slot2, cnt, basee);
  moe_kernel<<<49 * 6 * 8, 256, 0, stream>>>(Xb, expwT, cnt, basee, lst_tok, EO);
  combine_kernel<<<2322, 256, 0, stream>>>(EO, te1, te2, tw1, tw2, slot1, slot2,
                                           exp_b, MOEb);
  qkv_kernel<<<768, 256, 0, stream>>>(MOEb, wT, bq, bk, bv, Qb, Kb, V);
  attn_kernel<<<512, 256, 0, stream>>>(Qb, Kb, PBAR);
  pv_kernel<<<dim3(16, 3), 256, 0, stream>>>(PBAR, V, CTX);
  ln_dot_kernel<<<512, 256, 0, stream>>>(CTX, MOEb, ecls, mcls, ln_w, ln_b, outp);
}